// Round 6
// baseline (153.404 us; speedup 1.0000x reference)
//
#include <hip/hip_runtime.h>
#include <hip/hip_bf16.h>

#define N_NODES 1536
#define NF 64
#define NOUT 64
#define FIN 65
#define TI 8

typedef __bf16 bf16x8 __attribute__((ext_vector_type(8)));
typedef float f32x4 __attribute__((ext_vector_type(4)));

// One block: TI=8 i-rows x 128 j-cols. Swapped-operand MFMA
//   D[o][j] = sum_k W[o][k] * |feat[j][k]-feat[i][k]|
// Epilogue transposes each wave's 32j x 64o tile through wave-private
// XOR-swizzled LDS (1 KB lane-contiguous stores). Store registers are
// double-buffered (Ra/Rb) and stores are deferred one compute phase, so
// each wave keeps ~16 stores in flight and the vmcnt reuse-wait for a
// register set lands a full iteration after its stores issue.
__global__ __launch_bounds__(256, 2)
void edge_gcn_mfma(const float* __restrict__ feat,
                   const float* __restrict__ adj,
                   const float* __restrict__ W,
                   const float* __restrict__ b,
                   float* __restrict__ out)
{
    const int tid  = threadIdx.x;
    const int lane = tid & 63;
    const int wv   = tid >> 6;          // wave 0..3
    const int l15  = lane & 15;
    const int lg   = lane >> 4;         // 0..3

    const int i0 = blockIdx.y * TI;
    const int j0 = blockIdx.x * 128;
    const int jw = j0 + wv * 32;        // this wave's 32 j's

    // 4 waves x 2048 floats (8 KB) = 32 KB, wave-private regions
    __shared__ float lds[8192];
    float* const lbase = lds + wv * 2048;

    // ---- A fragments (W): once per block ----
    bf16x8 afrag[2][4];                 // [kk][mo]
#pragma unroll
    for (int kk = 0; kk < 2; ++kk) {
#pragma unroll
        for (int mo = 0; mo < 4; ++mo) {
            const float* wp = W + (mo * 16 + l15) * FIN + kk * 32 + lg * 8;
#pragma unroll
            for (int e = 0; e < 8; ++e) afrag[kk][mo][e] = (__bf16)wp[e];
        }
    }

    // ---- feat[j] fragments: once per block ----
    float fjr[2][2][8];                 // [n][kk][e]
#pragma unroll
    for (int n = 0; n < 2; ++n) {
        const float* fjrow = feat + (jw + n * 16 + l15) * NF;
#pragma unroll
        for (int kk = 0; kk < 2; ++kk)
#pragma unroll
            for (int e = 0; e < 8; ++e)
                fjr[n][kk][e] = fjrow[kk * 32 + lg * 8 + e];
    }

    // ---- adjacency-channel weights + bias (o = mo*16 + lg*4 + r): once ----
    float wl[4][4], bv[4][4];
#pragma unroll
    for (int mo = 0; mo < 4; ++mo) {
        const float* bp = b + mo * 16 + lg * 4;
#pragma unroll
        for (int r = 0; r < 4; ++r) {
            bv[mo][r] = bp[r];
            wl[mo][r] = W[(mo * 16 + lg * 4 + r) * FIN + NF];
        }
    }

    // ---- helpers ----
    auto compute_to_lds = [&](int i) {
        float fi[2][8];
#pragma unroll
        for (int kk = 0; kk < 2; ++kk) {
            const float* fp = feat + i * NF + kk * 32 + lg * 8;
#pragma unroll
            for (int e = 0; e < 8; ++e) fi[kk][e] = fp[e];
        }

        f32x4 acc[4][2];                // [mo][n], bias folded into init
#pragma unroll
        for (int mo = 0; mo < 4; ++mo)
#pragma unroll
            for (int n = 0; n < 2; ++n)
#pragma unroll
                for (int r = 0; r < 4; ++r)
                    acc[mo][n][r] = bv[mo][r];

#pragma unroll
        for (int n = 0; n < 2; ++n) {
#pragma unroll
            for (int kk = 0; kk < 2; ++kk) {
                bf16x8 bfrag;
#pragma unroll
                for (int e = 0; e < 8; ++e)
                    bfrag[e] = (__bf16)fabsf(fjr[n][kk][e] - fi[kk][e]);
#pragma unroll
                for (int mo = 0; mo < 4; ++mo)
                    acc[mo][n] = __builtin_amdgcn_mfma_f32_16x16x32_bf16(
                        afrag[kk][mo], bfrag, acc[mo][n], 0, 0, 0);
            }
        }

        // finalize + transposed LDS write: off = j*64 + (o ^ ((j&7)<<2))
#pragma unroll
        for (int n = 0; n < 2; ++n) {
            const int jrow = n * 16 + l15;
            const float av = adj[(size_t)i * N_NODES + jw + jrow];
#pragma unroll
            for (int mo = 0; mo < 4; ++mo) {
                f32x4 v;
#pragma unroll
                for (int r = 0; r < 4; ++r)
                    v[r] = acc[mo][n][r] + av * wl[mo][r];
                const int swz = (mo * 16 + lg * 4) ^ ((l15 & 7) << 2);
                *reinterpret_cast<f32x4*>(lbase + jrow * 64 + swz) = v;
            }
        }
    };

    auto ds_read_tile = [&](f32x4* R) {
#pragma unroll
        for (int t = 0; t < 8; ++t) {
            const int jr = t * 4 + lg;
            const int oo = l15 * 4;
            R[t] = *reinterpret_cast<const f32x4*>(
                lbase + jr * 64 + (oo ^ ((jr & 7) << 2)));
        }
    };

    auto store_tile = [&](const f32x4* R, int i) {
        float* const orow = out + ((size_t)i * N_NODES + jw) * NOUT + l15 * 4;
#pragma unroll
        for (int t = 0; t < 8; ++t)
            *reinterpret_cast<f32x4*>(orow + (t * 4 + lg) * NOUT) = R[t];
    };

    // ---- pipelined i loop: pairs (even, odd) ----
    f32x4 Ra[8], Rb[8];
    for (int ii = 0; ii < TI; ii += 2) {
        compute_to_lds(i0 + ii);
        if (ii) store_tile(Rb, i0 + ii - 1);   // overlap ds_read latency
        ds_read_tile(Ra);

        compute_to_lds(i0 + ii + 1);
        store_tile(Ra, i0 + ii);
        ds_read_tile(Rb);
    }
    store_tile(Rb, i0 + TI - 1);
}

extern "C" void kernel_launch(void* const* d_in, const int* in_sizes, int n_in,
                              void* d_out, int out_size, void* d_ws, size_t ws_size,
                              hipStream_t stream) {
    const float* feat = (const float*)d_in[0];   // [1536][64]
    const float* adj  = (const float*)d_in[1];   // [1536][1536]
    const float* W    = (const float*)d_in[2];   // [64][65]
    const float* b    = (const float*)d_in[3];   // [64]
    float* out = (float*)d_out;                  // [1536*1536][64]

    dim3 grid(N_NODES / 128, N_NODES / TI);
    dim3 block(256);
    edge_gcn_mfma<<<grid, block, 0, stream>>>(feat, adj, W, b, out);
}

// Round 7
// 132.239 us; speedup vs baseline: 1.1601x; 1.1601x over previous
//
#include <hip/hip_runtime.h>
#include <hip/hip_bf16.h>

#define N_NODES 1536
#define NF 64
#define NOUT 64
#define FIN 65
#define TI 8

typedef __bf16 bf16x8 __attribute__((ext_vector_type(8)));
typedef float f32x4 __attribute__((ext_vector_type(4)));

// One block: TI=8 i-rows x 128 j-cols. Swapped-operand MFMA
//   D[o][j] = sum_k W[o][k] * |feat[j][k]-feat[i][k]|
// All 16 adj values a wave needs are prefetched in one burst at kernel
// entry: adj is read exactly once globally, so every adj load is a
// guaranteed HBM miss (~1-2k cy) that otherwise sits on each iteration's
// critical path with only 2 waves/SIMD to hide it. Epilogue transposes
// each wave's 32j x 64o tile through wave-private XOR-swizzled LDS so
// global stores are 1 KB lane-contiguous full lines.
__global__ __launch_bounds__(256, 2)
void edge_gcn_mfma(const float* __restrict__ feat,
                   const float* __restrict__ adj,
                   const float* __restrict__ W,
                   const float* __restrict__ b,
                   float* __restrict__ out)
{
    const int tid  = threadIdx.x;
    const int lane = tid & 63;
    const int wv   = tid >> 6;          // wave 0..3
    const int l15  = lane & 15;
    const int lg   = lane >> 4;         // 0..3

    const int i0 = blockIdx.y * TI;
    const int j0 = blockIdx.x * 128;
    const int jw = j0 + wv * 32;        // this wave's 32 j's

    // 4 waves x 2048 floats (8 KB) = 32 KB, wave-private regions
    __shared__ float lds[8192];
    float* const lbase = lds + wv * 2048;

    // ---- adj prefetch: 16 independent HBM loads, issued first ----
    float av_pre[TI][2];
#pragma unroll
    for (int ii = 0; ii < TI; ++ii)
#pragma unroll
        for (int n = 0; n < 2; ++n)
            av_pre[ii][n] =
                adj[(size_t)(i0 + ii) * N_NODES + jw + n * 16 + l15];

    // ---- A fragments (W): once per block ----
    bf16x8 afrag[2][4];                 // [kk][mo]
#pragma unroll
    for (int kk = 0; kk < 2; ++kk) {
#pragma unroll
        for (int mo = 0; mo < 4; ++mo) {
            const float* wp = W + (mo * 16 + l15) * FIN + kk * 32 + lg * 8;
#pragma unroll
            for (int e = 0; e < 8; ++e) afrag[kk][mo][e] = (__bf16)wp[e];
        }
    }

    // ---- feat[j] fragments: once per block ----
    float fjr[2][2][8];                 // [n][kk][e]
#pragma unroll
    for (int n = 0; n < 2; ++n) {
        const float* fjrow = feat + (jw + n * 16 + l15) * NF;
#pragma unroll
        for (int kk = 0; kk < 2; ++kk)
#pragma unroll
            for (int e = 0; e < 8; ++e)
                fjr[n][kk][e] = fjrow[kk * 32 + lg * 8 + e];
    }

    // ---- adjacency-channel weights + bias (o = mo*16 + lg*4 + r): once ----
    float wl[4][4], bv[4][4];
#pragma unroll
    for (int mo = 0; mo < 4; ++mo) {
        const float* bp = b + mo * 16 + lg * 4;
#pragma unroll
        for (int r = 0; r < 4; ++r) {
            bv[mo][r] = bp[r];
            wl[mo][r] = W[(mo * 16 + lg * 4 + r) * FIN + NF];
        }
    }

    // ---- i loop (fully unrolled: av_pre statically indexed) ----
#pragma unroll
    for (int ii = 0; ii < TI; ++ii) {
        const int i = i0 + ii;

        float fi[2][8];
#pragma unroll
        for (int kk = 0; kk < 2; ++kk) {
            const float* fp = feat + i * NF + kk * 32 + lg * 8;
#pragma unroll
            for (int e = 0; e < 8; ++e) fi[kk][e] = fp[e];
        }

        f32x4 acc[4][2];                // [mo][n], bias folded into init
#pragma unroll
        for (int mo = 0; mo < 4; ++mo)
#pragma unroll
            for (int n = 0; n < 2; ++n)
#pragma unroll
                for (int r = 0; r < 4; ++r)
                    acc[mo][n][r] = bv[mo][r];

#pragma unroll
        for (int n = 0; n < 2; ++n) {
#pragma unroll
            for (int kk = 0; kk < 2; ++kk) {
                bf16x8 bfrag;
#pragma unroll
                for (int e = 0; e < 8; ++e)
                    bfrag[e] = (__bf16)fabsf(fjr[n][kk][e] - fi[kk][e]);
#pragma unroll
                for (int mo = 0; mo < 4; ++mo)
                    acc[mo][n] = __builtin_amdgcn_mfma_f32_16x16x32_bf16(
                        afrag[kk][mo], bfrag, acc[mo][n], 0, 0, 0);
            }
        }

        // ---- epilogue A: finalize + write transposed tile into LDS ----
        // tile T[j(32)][o(64)], float off = j*64 + (o ^ ((j&7)<<2))
#pragma unroll
        for (int n = 0; n < 2; ++n) {
            const int jrow = n * 16 + l15;
            const float av = av_pre[ii][n];
#pragma unroll
            for (int mo = 0; mo < 4; ++mo) {
                f32x4 v;
#pragma unroll
                for (int r = 0; r < 4; ++r)
                    v[r] = acc[mo][n][r] + av * wl[mo][r];
                const int swz = (mo * 16 + lg * 4) ^ ((l15 & 7) << 2);
                *reinterpret_cast<f32x4*>(lbase + jrow * 64 + swz) = v;
            }
        }

        // ---- epilogue B: read lane-contiguous, 1 KB stores ----
#pragma unroll
        for (int t = 0; t < 8; ++t) {
            const int jr = t * 4 + lg;
            const int oo = l15 * 4;
            f32x4 v = *reinterpret_cast<const f32x4*>(
                lbase + jr * 64 + (oo ^ ((jr & 7) << 2)));
            float* op = out + ((size_t)i * N_NODES + jw + jr) * NOUT + oo;
            *reinterpret_cast<f32x4*>(op) = v;
        }
    }
}

extern "C" void kernel_launch(void* const* d_in, const int* in_sizes, int n_in,
                              void* d_out, int out_size, void* d_ws, size_t ws_size,
                              hipStream_t stream) {
    const float* feat = (const float*)d_in[0];   // [1536][64]
    const float* adj  = (const float*)d_in[1];   // [1536][1536]
    const float* W    = (const float*)d_in[2];   // [64][65]
    const float* b    = (const float*)d_in[3];   // [64]
    float* out = (float*)d_out;                  // [1536*1536][64]

    dim3 grid(N_NODES / 128, N_NODES / TI);
    dim3 block(256);
    edge_gcn_mfma<<<grid, block, 0, stream>>>(feat, adj, W, b, out);
}

// Round 8
// 128.091 us; speedup vs baseline: 1.1976x; 1.0324x over previous
//
#include <hip/hip_runtime.h>
#include <hip/hip_bf16.h>

#define N_NODES 1536
#define NF 64
#define NOUT 64
#define FIN 65
#define TI 8

typedef __bf16 bf16x8 __attribute__((ext_vector_type(8)));
typedef float f32x4 __attribute__((ext_vector_type(4)));

// One block: TI=8 i-rows x 128 j-cols. Swapped-operand MFMA
//   D[o][j] = sum_k W[o][k] * |feat[j][k]-feat[i][k]|
// All global LOADS are hoisted out of the i-loop: adj tile -> registers,
// feat i-slab -> LDS (read back via ds_read, lgkmcnt). The loop body then
// has only DS ops + stores, so no s_waitcnt vmcnt(N) for a load can force
// the wave to drain its outstanding stores (vmcnt is shared by loads AND
// stores) -> stores stream instead of bursting. Epilogue transposes each
// wave's 32j x 64o tile through wave-private XOR-swizzled LDS so global
// stores are 1 KB lane-contiguous full lines.
__global__ __launch_bounds__(256, 2)
void edge_gcn_mfma(const float* __restrict__ feat,
                   const float* __restrict__ adj,
                   const float* __restrict__ W,
                   const float* __restrict__ b,
                   float* __restrict__ out)
{
    const int tid  = threadIdx.x;
    const int lane = tid & 63;
    const int wv   = tid >> 6;          // wave 0..3
    const int l15  = lane & 15;
    const int lg   = lane >> 4;         // 0..3

    const int i0 = blockIdx.y * TI;
    const int j0 = blockIdx.x * 128;
    const int jw = j0 + wv * 32;        // this wave's 32 j's

    // 4 waves x 2048 floats (8 KB) transpose buffers + 512-float feat slab
    __shared__ float lds[8192];
    __shared__ float fslab[TI * NF];
    float* const lbase = lds + wv * 2048;

    // ---- cooperative feat i-slab load: 8 rows x 64 f32 = 128 x f32x4 ----
    if (tid < 128) {
        const int row = tid >> 4;            // 0..7
        const int col = (tid & 15) * 4;      // 0..60
        *reinterpret_cast<f32x4*>(&fslab[row * NF + col]) =
            *reinterpret_cast<const f32x4*>(&feat[(size_t)(i0 + row) * NF + col]);
    }

    // ---- adj prefetch: 16 independent HBM loads ----
    float av_pre[TI][2];
#pragma unroll
    for (int ii = 0; ii < TI; ++ii)
#pragma unroll
        for (int n = 0; n < 2; ++n)
            av_pre[ii][n] =
                adj[(size_t)(i0 + ii) * N_NODES + jw + n * 16 + l15];

    // ---- A fragments (W): once per block ----
    bf16x8 afrag[2][4];                 // [kk][mo]
#pragma unroll
    for (int kk = 0; kk < 2; ++kk) {
#pragma unroll
        for (int mo = 0; mo < 4; ++mo) {
            const float* wp = W + (mo * 16 + l15) * FIN + kk * 32 + lg * 8;
#pragma unroll
            for (int e = 0; e < 8; ++e) afrag[kk][mo][e] = (__bf16)wp[e];
        }
    }

    // ---- feat[j] fragments: once per block ----
    float fjr[2][2][8];                 // [n][kk][e]
#pragma unroll
    for (int n = 0; n < 2; ++n) {
        const float* fjrow = feat + (jw + n * 16 + l15) * NF;
#pragma unroll
        for (int kk = 0; kk < 2; ++kk)
#pragma unroll
            for (int e = 0; e < 8; ++e)
                fjr[n][kk][e] = fjrow[kk * 32 + lg * 8 + e];
    }

    // ---- adjacency-channel weights + bias (o = mo*16 + lg*4 + r): once ----
    float wl[4][4], bv[4][4];
#pragma unroll
    for (int mo = 0; mo < 4; ++mo) {
        const float* bp = b + mo * 16 + lg * 4;
#pragma unroll
        for (int r = 0; r < 4; ++r) {
            bv[mo][r] = bp[r];
            wl[mo][r] = W[(mo * 16 + lg * 4 + r) * FIN + NF];
        }
    }

    __syncthreads();                    // fslab ready; only barrier

    // ---- i loop (fully unrolled; loop body has NO global loads) ----
#pragma unroll
    for (int ii = 0; ii < TI; ++ii) {
        const int i = i0 + ii;

        float fi[2][8];                 // from LDS (broadcast, conflict-free)
#pragma unroll
        for (int kk = 0; kk < 2; ++kk) {
            const float* fp = &fslab[ii * NF + kk * 32 + lg * 8];
#pragma unroll
            for (int e = 0; e < 8; ++e) fi[kk][e] = fp[e];
        }

        f32x4 acc[4][2];                // [mo][n], bias folded into init
#pragma unroll
        for (int mo = 0; mo < 4; ++mo)
#pragma unroll
            for (int n = 0; n < 2; ++n)
#pragma unroll
                for (int r = 0; r < 4; ++r)
                    acc[mo][n][r] = bv[mo][r];

#pragma unroll
        for (int n = 0; n < 2; ++n) {
#pragma unroll
            for (int kk = 0; kk < 2; ++kk) {
                bf16x8 bfrag;
#pragma unroll
                for (int e = 0; e < 8; ++e)
                    bfrag[e] = (__bf16)fabsf(fjr[n][kk][e] - fi[kk][e]);
#pragma unroll
                for (int mo = 0; mo < 4; ++mo)
                    acc[mo][n] = __builtin_amdgcn_mfma_f32_16x16x32_bf16(
                        afrag[kk][mo], bfrag, acc[mo][n], 0, 0, 0);
            }
        }

        // ---- epilogue A: finalize + write transposed tile into LDS ----
        // tile T[j(32)][o(64)], float off = j*64 + (o ^ ((j&7)<<2))
#pragma unroll
        for (int n = 0; n < 2; ++n) {
            const int jrow = n * 16 + l15;
            const float av = av_pre[ii][n];
#pragma unroll
            for (int mo = 0; mo < 4; ++mo) {
                f32x4 v;
#pragma unroll
                for (int r = 0; r < 4; ++r)
                    v[r] = acc[mo][n][r] + av * wl[mo][r];
                const int swz = (mo * 16 + lg * 4) ^ ((l15 & 7) << 2);
                *reinterpret_cast<f32x4*>(lbase + jrow * 64 + swz) = v;
            }
        }

        // ---- epilogue B: read lane-contiguous, 1 KB stores ----
#pragma unroll
        for (int t = 0; t < 8; ++t) {
            const int jr = t * 4 + lg;
            const int oo = l15 * 4;
            f32x4 v = *reinterpret_cast<const f32x4*>(
                lbase + jr * 64 + (oo ^ ((jr & 7) << 2)));
            float* op = out + ((size_t)i * N_NODES + jw + jr) * NOUT + oo;
            *reinterpret_cast<f32x4*>(op) = v;
        }
    }
}

extern "C" void kernel_launch(void* const* d_in, const int* in_sizes, int n_in,
                              void* d_out, int out_size, void* d_ws, size_t ws_size,
                              hipStream_t stream) {
    const float* feat = (const float*)d_in[0];   // [1536][64]
    const float* adj  = (const float*)d_in[1];   // [1536][1536]
    const float* W    = (const float*)d_in[2];   // [64][65]
    const float* b    = (const float*)d_in[3];   // [64]
    float* out = (float*)d_out;                  // [1536*1536][64]

    dim3 grid(N_NODES / 128, N_NODES / TI);
    dim3 block(256);
    edge_gcn_mfma<<<grid, block, 0, stream>>>(feat, adj, W, b, out);
}

// Round 9
// 125.125 us; speedup vs baseline: 1.2260x; 1.0237x over previous
//
#include <hip/hip_runtime.h>
#include <hip/hip_bf16.h>

#define N_NODES 1536
#define NF 64
#define NOUT 64
#define FIN 65
#define TI 8

typedef __bf16 bf16x8 __attribute__((ext_vector_type(8)));
typedef float f32x4 __attribute__((ext_vector_type(4)));

// One block: TI=8 i-rows x 128 j-cols. Swapped-operand MFMA
//   D[o][j] = sum_k W[o][k] * |feat[j][k]-feat[i][k]|
// 3 blocks/CU (launch_bounds(256,3)): 2304 blocks / 256 CU = 9/CU = exactly
// 3 dispatch rounds (was 4.5 at 2/CU -> half-round tail ~11%), and the odd
// slot count staggers block setup phases against neighbors' store phases.
// Register diet to fit the ~170-VGPR cap: adj tile lives in a 4 KB LDS slab,
// adj/bias finalize moved AFTER the transpose (needs only wlB[4]+bvB[4]),
// acc inits to zero, i-loop forced rolled. All global loads stay hoisted
// out of the i-loop (only DS ops + stores inside). Epilogue transposes each
// wave's 32j x 64o tile through wave-private XOR-swizzled LDS so global
// stores are 1 KB lane-contiguous full lines.
__global__ __launch_bounds__(256, 3)
void edge_gcn_mfma(const float* __restrict__ feat,
                   const float* __restrict__ adj,
                   const float* __restrict__ W,
                   const float* __restrict__ b,
                   float* __restrict__ out)
{
    const int tid  = threadIdx.x;
    const int lane = tid & 63;
    const int wv   = tid >> 6;          // wave 0..3
    const int l15  = lane & 15;
    const int lg   = lane >> 4;         // 0..3

    const int i0 = blockIdx.y * TI;
    const int j0 = blockIdx.x * 128;
    const int jw = j0 + wv * 32;        // this wave's 32 j's

    __shared__ float lds[8192];         // 4 waves x 8 KB transpose buffers
    __shared__ float fslab[TI * NF];    // 8 x 64 feat i-slab (2 KB)
    __shared__ float aslab[TI * 128];   // 8 x 128 adj tile (4 KB)
    float* const lbase = lds + wv * 2048;

    // ---- cooperative feat i-slab load: 8 rows x 64 f32 ----
    if (tid < 128) {
        const int row = tid >> 4;            // 0..7
        const int col = (tid & 15) * 4;      // 0..60
        *reinterpret_cast<f32x4*>(&fslab[row * NF + col]) =
            *reinterpret_cast<const f32x4*>(&feat[(size_t)(i0 + row) * NF + col]);
    }
    // ---- cooperative adj tile load: 8 rows x 128 f32 ----
    {
        const int row = tid >> 5;            // 0..7
        const int col = (tid & 31) * 4;      // 0..124
        *reinterpret_cast<f32x4*>(&aslab[row * 128 + col]) =
            *reinterpret_cast<const f32x4*>(
                &adj[(size_t)(i0 + row) * N_NODES + j0 + col]);
    }

    // ---- A fragments (W): once per block ----
    bf16x8 afrag[2][4];                 // [kk][mo]
#pragma unroll
    for (int kk = 0; kk < 2; ++kk) {
#pragma unroll
        for (int mo = 0; mo < 4; ++mo) {
            const float* wp = W + (mo * 16 + l15) * FIN + kk * 32 + lg * 8;
#pragma unroll
            for (int e = 0; e < 8; ++e) afrag[kk][mo][e] = (__bf16)wp[e];
        }
    }

    // ---- feat[j] fragments: once per block ----
    float fjr[2][2][8];                 // [n][kk][e]
#pragma unroll
    for (int n = 0; n < 2; ++n) {
        const float* fjrow = feat + (jw + n * 16 + l15) * NF;
#pragma unroll
        for (int kk = 0; kk < 2; ++kk)
#pragma unroll
            for (int e = 0; e < 8; ++e)
                fjr[n][kk][e] = fjrow[kk * 32 + lg * 8 + e];
    }

    // ---- epilogue-B constants: o = l15*4 + r ----
    float wlB[4], bvB[4];
#pragma unroll
    for (int r = 0; r < 4; ++r) {
        wlB[r] = W[(l15 * 4 + r) * FIN + NF];
        bvB[r] = b[l15 * 4 + r];
    }

    __syncthreads();                    // slabs ready; only barrier

    // ---- i loop (rolled: low VGPR; body has NO global loads) ----
#pragma unroll 1
    for (int ii = 0; ii < TI; ++ii) {
        const int i = i0 + ii;

        float fi[2][8];                 // from LDS (broadcast, conflict-free)
#pragma unroll
        for (int kk = 0; kk < 2; ++kk) {
            const float* fp = &fslab[ii * NF + kk * 32 + lg * 8];
#pragma unroll
            for (int e = 0; e < 8; ++e) fi[kk][e] = fp[e];
        }

        f32x4 acc[4][2];                // [mo][n]
#pragma unroll
        for (int mo = 0; mo < 4; ++mo)
#pragma unroll
            for (int n = 0; n < 2; ++n)
                acc[mo][n] = (f32x4){0.f, 0.f, 0.f, 0.f};

#pragma unroll
        for (int n = 0; n < 2; ++n) {
#pragma unroll
            for (int kk = 0; kk < 2; ++kk) {
                bf16x8 bfrag;
#pragma unroll
                for (int e = 0; e < 8; ++e)
                    bfrag[e] = (__bf16)fabsf(fjr[n][kk][e] - fi[kk][e]);
#pragma unroll
                for (int mo = 0; mo < 4; ++mo)
                    acc[mo][n] = __builtin_amdgcn_mfma_f32_16x16x32_bf16(
                        afrag[kk][mo], bfrag, acc[mo][n], 0, 0, 0);
            }
        }

        // ---- epilogue A: raw acc -> transposed LDS tile ----
        // tile T[j(32)][o(64)], float off = j*64 + (o ^ ((j&7)<<2))
#pragma unroll
        for (int n = 0; n < 2; ++n) {
            const int jrow = n * 16 + l15;
#pragma unroll
            for (int mo = 0; mo < 4; ++mo) {
                const int swz = (mo * 16 + lg * 4) ^ ((l15 & 7) << 2);
                *reinterpret_cast<f32x4*>(lbase + jrow * 64 + swz) = acc[mo][n];
            }
        }

        // ---- epilogue B: finalize (+adj*W64 +bias) + 1 KB stores ----
#pragma unroll
        for (int t = 0; t < 8; ++t) {
            const int jr = t * 4 + lg;
            const int oo = l15 * 4;
            f32x4 v = *reinterpret_cast<const f32x4*>(
                lbase + jr * 64 + (oo ^ ((jr & 7) << 2)));
            const float av = aslab[ii * 128 + wv * 32 + jr];
#pragma unroll
            for (int r = 0; r < 4; ++r)
                v[r] = v[r] + av * wlB[r] + bvB[r];
            float* op = out + ((size_t)i * N_NODES + jw + jr) * NOUT + oo;
            *reinterpret_cast<f32x4*>(op) = v;
        }
    }
}

extern "C" void kernel_launch(void* const* d_in, const int* in_sizes, int n_in,
                              void* d_out, int out_size, void* d_ws, size_t ws_size,
                              hipStream_t stream) {
    const float* feat = (const float*)d_in[0];   // [1536][64]
    const float* adj  = (const float*)d_in[1];   // [1536][1536]
    const float* W    = (const float*)d_in[2];   // [64][65]
    const float* b    = (const float*)d_in[3];   // [64]
    float* out = (float*)d_out;                  // [1536*1536][64]

    dim3 grid(N_NODES / 128, N_NODES / TI);
    dim3 block(256);
    edge_gcn_mfma<<<grid, block, 0, stream>>>(feat, adj, W, b, out);
}